// Round 8
// baseline (1354.529 us; speedup 1.0000x reference)
//
#include <hip/hip_runtime.h>

// Problem constants (fixed by the reference)
constexpr int Bb = 32;     // batch
constexpr int Tt = 32;     // time steps
constexpr int Ii = 8192;   // input dim
constexpr int Hh = 8192;   // hidden dim
constexpr int Oo = 2048;   // output dim
constexpr int TB = Tt * Bb;  // 1024
constexpr int TCH = 4;       // timesteps per XCD chunk (4 MB x2 slice = 1 XCD L2)
constexpr int CAPP = 112;    // staged int4 pairs per row (224 entries; Poisson(128) max ~180)

// ---------------- x transpose: (B,T,I) -> (I,T,B) ----------------
__global__ void transpose_x_kernel(const float* __restrict__ x, float* __restrict__ x2) {
  int blk = blockIdx.x;
  int tp = blk >> 7;             // Ii/64 = 128
  int ib = blk & 127;
  int t0 = tp * 2;
  int i0 = ib * 64;
  __shared__ float lds[64][65];
  int tid = threadIdx.x;
  for (int idx = tid; idx < 64 * 64; idx += 256) {
    int row = idx >> 6;          // tt*32 + b
    int il  = idx & 63;
    int tt = row >> 5, bb = row & 31;
    lds[il][row] = x[(size_t)bb * Tt * Ii + (size_t)(t0 + tt) * Ii + i0 + il];
  }
  __syncthreads();
  for (int idx = tid; idx < 64 * 64; idx += 256) {
    int il = idx >> 6;
    int row = idx & 63;
    x2[(size_t)(i0 + il) * TB + t0 * Bb + row] = lds[il][row];
  }
}

// ---------------- CSR build (merged kernels) ----------------
__global__ void hist3_kernel(const int* __restrict__ r1, int n1, int* __restrict__ c1,
                             const int* __restrict__ r2, int n2, int* __restrict__ c2,
                             const int* __restrict__ r3, int n3, int* __restrict__ c3) {
  int i = blockIdx.x * blockDim.x + threadIdx.x;
  int stride = gridDim.x * blockDim.x;
  for (int j = i; j < n1; j += stride) atomicAdd(&c1[r1[j]], 1);
  for (int j = i; j < n2; j += stride) atomicAdd(&c2[r2[j]], 1);
  for (int j = i; j < n3; j += stride) atomicAdd(&c3[r3[j]], 1);
}

__global__ void scan3_kernel(int* __restrict__ c1, int n1, int* __restrict__ r1, int p1,
                             int* __restrict__ c2, int n2, int* __restrict__ r2, int p2,
                             int* __restrict__ c3, int n3, int* __restrict__ r3, int p3) {
  int* cnt_cursor; int n; int* row_start; int pad;
  if (blockIdx.x == 0)      { cnt_cursor = c1; n = n1; row_start = r1; pad = p1; }
  else if (blockIdx.x == 1) { cnt_cursor = c2; n = n2; row_start = r2; pad = p2; }
  else                      { cnt_cursor = c3; n = n3; row_start = r3; pad = p3; }
  __shared__ int sums[1024];
  int tid = threadIdx.x;
  int chunk = (n + 1023) >> 10;
  int base = tid * chunk;
  int s = 0;
  for (int i = 0; i < chunk; i++) {
    int idx = base + i;
    if (idx < n) {
      int v = cnt_cursor[idx];
      s += pad ? ((v + 1) & ~1) : v;
    }
  }
  sums[tid] = s;
  __syncthreads();
  for (int off = 1; off < 1024; off <<= 1) {
    int other = (tid >= off) ? sums[tid - off] : 0;
    __syncthreads();
    sums[tid] += other;
    __syncthreads();
  }
  int run = sums[tid] - s;
  for (int i = 0; i < chunk; i++) {
    int idx = base + i;
    if (idx < n) {
      int v = cnt_cursor[idx];
      row_start[idx] = run;
      cnt_cursor[idx] = run;
      run += pad ? ((v + 1) & ~1) : v;
    }
  }
  if (tid == 1023) row_start[n] = sums[1023];
}

__global__ void scatter3_kernel(
    const int* __restrict__ r1, const int* __restrict__ co1, const float* __restrict__ v1,
    int n1, int* __restrict__ cu1, int2* __restrict__ e1,
    const int* __restrict__ r2, const int* __restrict__ co2, const float* __restrict__ v2,
    int n2, int* __restrict__ cu2, int2* __restrict__ e2,
    const int* __restrict__ r3, const int* __restrict__ co3, const float* __restrict__ v3,
    int n3, int* __restrict__ cu3, int2* __restrict__ e3) {
  int i = blockIdx.x * blockDim.x + threadIdx.x;
  int stride = gridDim.x * blockDim.x;
  for (int j = i; j < n1; j += stride) {
    int pos = atomicAdd(&cu1[r1[j]], 1);
    e1[pos] = make_int2(co1[j], __float_as_int(v1[j]));
  }
  for (int j = i; j < n2; j += stride) {
    int pos = atomicAdd(&cu2[r2[j]], 1);
    e2[pos] = make_int2(co2[j], __float_as_int(v2[j]));
  }
  for (int j = i; j < n3; j += stride) {
    int pos = atomicAdd(&cu3[r3[j]], 1);
    e3[pos] = make_int2(co3[j], __float_as_int(v3[j]));
  }
}

// ---------------- preIH, XCD-pinned time chunks + entry prefetch ----------------
__global__ void __launch_bounds__(256, 8) preih_kernel(
    const int* __restrict__ ih_rs, const int* __restrict__ ih_cur,
    const int4* __restrict__ ih_entp,
    const float* __restrict__ hh_bias, const float* __restrict__ x2,
    float* __restrict__ preAll) {
  int xcd = blockIdx.x & 7;
  int r = ((blockIdx.x >> 3) << 2) + (threadIdx.x >> 6);
  int lane = threadIdx.x & 63;
  int t0 = xcd * TCH;
  int s0  = __builtin_amdgcn_readfirstlane(ih_rs[r]);
  int cnt = __builtin_amdgcn_readfirstlane(ih_cur[r]) - s0;
  int np = (cnt + 1) >> 1;
  const int4* ep = ih_entp + (s0 >> 1);
  const float* xch = x2 + t0 * Bb;

  float2 a0 = {0.f, 0.f}, a1 = {0.f, 0.f}, a2 = {0.f, 0.f}, a3 = {0.f, 0.f};
  int4 f0 = ep[0], f1 = ep[1];
  int m = 0;
  for (; m + 2 <= np; m += 2) {
    int4 e01 = f0;
    int4 e23 = f1;
    f0 = ep[m + 2];
    f1 = ep[m + 3];
    const float2* p0 = (const float2*)(xch + (size_t)e01.x * TB);
    const float2* p1 = (const float2*)(xch + (size_t)e01.z * TB);
    const float2* p2 = (const float2*)(xch + (size_t)e23.x * TB);
    const float2* p3 = (const float2*)(xch + (size_t)e23.z * TB);
    float2 x0 = p0[lane], x1 = p1[lane], x2v = p2[lane], x3 = p3[lane];
    float v0 = __int_as_float(e01.y), v1 = __int_as_float(e01.w);
    float v2 = __int_as_float(e23.y), v3 = __int_as_float(e23.w);
    a0.x += v0 * x0.x;  a0.y += v0 * x0.y;
    a1.x += v1 * x1.x;  a1.y += v1 * x1.y;
    a2.x += v2 * x2v.x; a2.y += v2 * x2v.y;
    a3.x += v3 * x3.x;  a3.y += v3 * x3.y;
  }
  if (m < np) {
    int4 e01 = f0;
    const float2* p0 = (const float2*)(xch + (size_t)e01.x * TB);
    const float2* p1 = (const float2*)(xch + (size_t)e01.z * TB);
    float2 x0 = p0[lane], x1 = p1[lane];
    float v0 = __int_as_float(e01.y), v1 = __int_as_float(e01.w);
    a0.x += v0 * x0.x; a0.y += v0 * x0.y;
    a1.x += v1 * x1.x; a1.y += v1 * x1.y;
  }
  float bias = hh_bias[r];
  float2 acc;
  acc.x = ((a0.x + a1.x) + (a2.x + a3.x)) + bias;
  acc.y = ((a0.y + a1.y) + (a2.y + a3.y)) + bias;
  int t = t0 + (lane >> 4);
  int b0 = (lane & 15) * 2;
  *(float2*)(preAll + ((size_t)t * Hh + r) * Bb + b0) = acc;
}

// ---------------- Persistent pipelined recurrence (one dispatch, 32 steps) ----------------
// All blocks co-resident (cooperative launch). Per step: compute h_{t+1} rows,
// store via agent-scope write-through (L3-visible, no dirty L2), then a light
// flag barrier: per-block arrival counter + go-flag polled by thread 0 only.
// hh entries staged in LDS ONCE for all 32 steps (R2 evidence: ~5us/step compute).
// Safety: h slots are written exactly once per launch and read only post-barrier,
// so normal cached gathers cannot see stale lines (dispatch boundary invalidated
// everything before this kernel started).
__global__ void __launch_bounds__(256, 8) rnn_pipe(
    const int* __restrict__ hh_rs, const int* __restrict__ hh_cur,
    const int4* __restrict__ hh_entp,
    const float* __restrict__ preAll, float* __restrict__ hAll,
    unsigned int* __restrict__ arrive, unsigned int* __restrict__ goflag,
    int nrw, int nwaves, unsigned int nblocks) {
  __shared__ int4 lent[8][CAPP];   // 14 KB: [wave*nrw slot][pair]
  int wib = threadIdx.x >> 6;
  int lane = threadIdx.x & 63;
  int h = lane >> 5, b = lane & 31;
  int wave = blockIdx.x * 4 + wib;

  // Stage each owned row's entry pairs into LDS once (step-invariant)
  int npv[2], s0v[2], npl[2];
  for (int ri = 0; ri < nrw; ri++) {
    int r = wave + ri * nwaves;
    int s0  = __builtin_amdgcn_readfirstlane(hh_rs[r]);       // even (pair-padded)
    int cnt = __builtin_amdgcn_readfirstlane(hh_cur[r]) - s0;
    int np = (cnt + 1) >> 1;
    s0v[ri] = s0; npv[ri] = np;
    int nl = np < CAPP ? np : CAPP;
    npl[ri] = nl;
    int slot = wib * 2 + ri;
    for (int m = lane; m < nl; m += 64) lent[slot][m] = hh_entp[(s0 >> 1) + m];
  }
  __syncthreads();

  const size_t HS = (size_t)Hh * Bb;
  for (int t = 0; t < Tt; t++) {
    const float* hprev = hAll + (size_t)t * HS;
    float* hnext       = hAll + (size_t)(t + 1) * HS;
    for (int ri = 0; ri < nrw; ri++) {
      int r = wave + ri * nwaves;
      int slot = wib * 2 + ri;
      int np = npv[ri], nl = npl[ri];
      float pre = preAll[((size_t)t * Hh + r) * Bb + b];
      float a0 = 0.f, a1 = 0.f, a2 = 0.f, a3 = 0.f;
      const int4* ep = lent[slot];
      int m = 0;
      for (; m + 4 <= nl; m += 4) {
        int4 e0 = ep[m], e1 = ep[m + 1], e2 = ep[m + 2], e3 = ep[m + 3];
        int   c0 = h ? e0.z : e0.x;  float v0 = __int_as_float(h ? e0.w : e0.y);
        int   c1 = h ? e1.z : e1.x;  float v1 = __int_as_float(h ? e1.w : e1.y);
        int   c2 = h ? e2.z : e2.x;  float v2 = __int_as_float(h ? e2.w : e2.y);
        int   c3 = h ? e3.z : e3.x;  float v3 = __int_as_float(h ? e3.w : e3.y);
        a0 += v0 * hprev[((size_t)c0 << 5) + b];
        a1 += v1 * hprev[((size_t)c1 << 5) + b];
        a2 += v2 * hprev[((size_t)c2 << 5) + b];
        a3 += v3 * hprev[((size_t)c3 << 5) + b];
      }
      for (; m < nl; m++) {
        int4 e = ep[m];
        int c = h ? e.z : e.x;  float v = __int_as_float(h ? e.w : e.y);
        a0 += v * hprev[((size_t)c << 5) + b];
      }
      // rare overflow tail from global
      for (m = nl; m < np; m++) {
        int4 e = hh_entp[(s0v[ri] >> 1) + m];
        int c = h ? e.z : e.x;  float v = __int_as_float(h ? e.w : e.y);
        a0 += v * hprev[((size_t)c << 5) + b];
      }
      float acc = (a0 + a1) + (a2 + a3);
      acc += __shfl_xor(acc, 32, 64);
      float hv = 1.0f / (1.0f + __expf(-(pre + acc)));
      if (h == 0)
        __hip_atomic_store(&hnext[((size_t)r << 5) + b], hv,
                           __ATOMIC_RELAXED, __HIP_MEMORY_SCOPE_AGENT);
    }
    // Light grid barrier: __syncthreads drains all block stores (vmcnt(0) before
    // s_barrier), then one arrival add per block; thread 0 spins on go-flag.
    __syncthreads();
    if (threadIdx.x == 0) {
      unsigned int old = __hip_atomic_fetch_add(&arrive[t], 1u,
                             __ATOMIC_RELEASE, __HIP_MEMORY_SCOPE_AGENT);
      if (old == nblocks - 1u) {
        __hip_atomic_store(&goflag[t], 1u, __ATOMIC_RELEASE, __HIP_MEMORY_SCOPE_AGENT);
      } else {
        int spins = 0;
        while (__hip_atomic_load(&goflag[t], __ATOMIC_RELAXED,
                                 __HIP_MEMORY_SCOPE_AGENT) == 0u) {
          __builtin_amdgcn_s_sleep(16);
          if (++spins > (1 << 22)) break;   // hang guard; never triggers if correct
        }
      }
    }
    __syncthreads();
  }
}

// ---------------- Fallback: one dispatch per step (R7 path) ----------------
__global__ void __launch_bounds__(256, 8) step_kernel(
    const int* __restrict__ hh_rs, const int* __restrict__ hh_cur,
    const int4* __restrict__ hh_entp,
    const float* __restrict__ pre_t,
    const float* __restrict__ hprev,
    float* __restrict__ hnext) {
  int r = (blockIdx.x * 256 + threadIdx.x) >> 6;
  int lane = threadIdx.x & 63;
  int h = lane >> 5, b = lane & 31;
  int s0  = __builtin_amdgcn_readfirstlane(hh_rs[r]);
  int cnt = __builtin_amdgcn_readfirstlane(hh_cur[r]) - s0;
  int np = (cnt + 1) >> 1;
  const int4* ep = hh_entp + (s0 >> 1);
  float pre = pre_t[r * Bb + b];

  float a0 = 0.f, a1 = 0.f, a2 = 0.f, a3 = 0.f;
  int m = 0;
  for (; m + 4 <= np; m += 4) {
    int4 e0 = ep[m], e1 = ep[m + 1], e2 = ep[m + 2], e3 = ep[m + 3];
    int   c0 = h ? e0.z : e0.x;  float v0 = __int_as_float(h ? e0.w : e0.y);
    int   c1 = h ? e1.z : e1.x;  float v1 = __int_as_float(h ? e1.w : e1.y);
    int   c2 = h ? e2.z : e2.x;  float v2 = __int_as_float(h ? e2.w : e2.y);
    int   c3 = h ? e3.z : e3.x;  float v3 = __int_as_float(h ? e3.w : e3.y);
    a0 += v0 * hprev[(c0 << 5) + b];
    a1 += v1 * hprev[(c1 << 5) + b];
    a2 += v2 * hprev[(c2 << 5) + b];
    a3 += v3 * hprev[(c3 << 5) + b];
  }
  for (; m < np; m++) {
    int4 e = ep[m];
    int c = h ? e.z : e.x;  float v = __int_as_float(h ? e.w : e.y);
    a0 += v * hprev[(c << 5) + b];
  }
  float acc = (a0 + a1) + (a2 + a3);
  acc += __shfl_xor(acc, 32, 64);
  float hv = 1.0f / (1.0f + __expf(-(pre + acc)));
  if (h == 0) hnext[(r << 5) + b] = hv;
}

// ---------------- Output spmm, XCD-partitioned by time ----------------
__global__ void __launch_bounds__(256, 8) out_kernel(
    const int* __restrict__ ho_rs, const int* __restrict__ ho_cur,
    const int4* __restrict__ ho_entp,
    const float* __restrict__ ho_bias, const float* __restrict__ hAll,
    float* __restrict__ out_tmp) {
  int xcd = blockIdx.x & 7;
  int w   = (blockIdx.x >> 3) * 4 + (threadIdx.x >> 6);
  int lane = threadIdx.x & 63;
  int h = lane >> 5, b = lane & 31;
  int t0 = xcd * 4;
  const float* hbase = hAll + (size_t)(t0 + 1) * (Hh * Bb);
  constexpr size_t HS = (size_t)Hh * Bb;

  for (int o = w; o < Oo; o += 1024) {
    int s0  = __builtin_amdgcn_readfirstlane(ho_rs[o]);
    int cnt = __builtin_amdgcn_readfirstlane(ho_cur[o]) - s0;
    int np = (cnt + 1) >> 1;
    const int4* ep = ho_entp + (s0 >> 1);
    float bias = (h == 0) ? ho_bias[o] : 0.f;
    float A0 = bias, A1 = bias, A2 = bias, A3 = bias;
    float B0 = 0.f, B1 = 0.f, B2 = 0.f, B3 = 0.f;
    int m = 0;
    for (; m + 2 <= np; m += 2) {
      int4 ea = ep[m];
      int4 eb = ep[m + 1];
      int ca = (h ? ea.z : ea.x);  float va = __int_as_float(h ? ea.w : ea.y);
      int cb = (h ? eb.z : eb.x);  float vb = __int_as_float(h ? eb.w : eb.y);
      const float* pa = hbase + ((size_t)ca << 5) + b;
      const float* pb = hbase + ((size_t)cb << 5) + b;
      A0 += va * pa[0];
      A1 += va * pa[HS];
      A2 += va * pa[2 * HS];
      A3 += va * pa[3 * HS];
      B0 += vb * pb[0];
      B1 += vb * pb[HS];
      B2 += vb * pb[2 * HS];
      B3 += vb * pb[3 * HS];
    }
    if (m < np) {
      int4 ea = ep[m];
      int ca = (h ? ea.z : ea.x);  float va = __int_as_float(h ? ea.w : ea.y);
      const float* pa = hbase + ((size_t)ca << 5) + b;
      A0 += va * pa[0];
      A1 += va * pa[HS];
      A2 += va * pa[2 * HS];
      A3 += va * pa[3 * HS];
    }
    A0 += B0; A1 += B1; A2 += B2; A3 += B3;
    A0 += __shfl_xor(A0, 32, 64);
    A1 += __shfl_xor(A1, 32, 64);
    A2 += __shfl_xor(A2, 32, 64);
    A3 += __shfl_xor(A3, 32, 64);
    if (h == 0) {
      out_tmp[((size_t)(t0 + 0) * Oo + o) * Bb + b] = A0;
      out_tmp[((size_t)(t0 + 1) * Oo + o) * Bb + b] = A1;
      out_tmp[((size_t)(t0 + 2) * Oo + o) * Bb + b] = A2;
      out_tmp[((size_t)(t0 + 3) * Oo + o) * Bb + b] = A3;
    }
  }
}

// ---------------- out transpose: (T,O,B) -> (B,T,O) ----------------
__global__ void transpose_out_kernel(const float* __restrict__ out_tmp, float* __restrict__ dout) {
  int blk = blockIdx.x;
  int t  = blk >> 5;
  int o0 = (blk & 31) << 6;
  __shared__ float lds[64][33];
  int tid = threadIdx.x;
  for (int idx = tid; idx < 64 * 32; idx += 256) {
    int ol = idx >> 5, bb = idx & 31;
    lds[ol][bb] = out_tmp[(size_t)t * Oo * Bb + (size_t)(o0 + ol) * Bb + bb];
  }
  __syncthreads();
  for (int idx = tid; idx < 32 * 64; idx += 256) {
    int bb = idx >> 6, ol = idx & 63;
    dout[(size_t)bb * Tt * Oo + (size_t)t * Oo + o0 + ol] = lds[ol][bb];
  }
}

extern "C" void kernel_launch(void* const* d_in, const int* in_sizes, int n_in,
                              void* d_out, int out_size, void* d_ws, size_t ws_size,
                              hipStream_t stream) {
  const float* x       = (const float*)d_in[0];
  const int*   hh_rows = (const int*)d_in[1];
  const int*   hh_cols = (const int*)d_in[2];
  const float* hh_vals = (const float*)d_in[3];
  const float* hh_bias = (const float*)d_in[4];
  const int*   ih_rows = (const int*)d_in[5];
  const int*   ih_cols = (const int*)d_in[6];
  const float* ih_vals = (const float*)d_in[7];
  const int*   ho_rows = (const int*)d_in[8];
  const int*   ho_cols = (const int*)d_in[9];
  const float* ho_vals = (const float*)d_in[10];
  const float* ho_bias = (const float*)d_in[11];
  float* out = (float*)d_out;

  const int nnz_hh = in_sizes[1];
  const int nnz_ih = in_sizes[5];
  const int nnz_ho = in_sizes[8];

  // Workspace carve-up
  char* w = (char*)d_ws;
  size_t off = 0;
  auto alloc = [&](size_t bytes) -> void* {
    void* p = w + off;
    off += (bytes + 255) & ~(size_t)255;
    return p;
  };
  float* x2      = (float*)alloc(sizeof(float) * (size_t)Ii * TB);              // 32 MB
  float* hAll    = (float*)alloc(sizeof(float) * (size_t)(Tt + 1) * Hh * Bb);   // 33 MB
  float* preAll  = (float*)alloc(sizeof(float) * (size_t)Tt * Hh * Bb);         // 32 MB
  int*  ih_rs  = (int*)alloc(4 * (size_t)(Hh + 1));
  int*  hh_rs  = (int*)alloc(4 * (size_t)(Hh + 1));
  int*  ho_rs  = (int*)alloc(4 * (size_t)(Oo + 1));
  // zero-init region: cursors + barrier state (one memset)
  size_t zero_off0 = off;
  int*  cur_all = (int*)alloc(4 * (size_t)(Hh + Hh + Oo));
  int*  ih_cur = cur_all;
  int*  hh_cur = cur_all + Hh;
  int*  ho_cur = cur_all + 2 * Hh;
  unsigned int* arrive = (unsigned int*)alloc(4 * (size_t)Tt);
  unsigned int* goflag = (unsigned int*)alloc(4 * (size_t)Tt);
  size_t zero_bytes = off - zero_off0;
  size_t ent_off0 = off;
  int2* ih_ent = (int2*)alloc(8 * ((size_t)nnz_ih + Hh + 8));   // pair-padded
  int2* hh_ent = (int2*)alloc(8 * ((size_t)nnz_hh + Hh + 8));   // pair-padded
  int2* ho_ent = (int2*)alloc(8 * ((size_t)nnz_ho + Oo + 8));   // pair-padded
  size_t ent_bytes = off - ent_off0;
  float* out_tmp = x2;   // alias: x2 dead after preih_kernel

  // Init (3 memsets)
  hipMemsetAsync(hAll, 0, sizeof(float) * (size_t)Hh * Bb, stream);   // h_{-1} = 0
  hipMemsetAsync(w + zero_off0, 0, zero_bytes, stream);
  hipMemsetAsync(w + ent_off0, 0, ent_bytes, stream);

  // x -> (I,T,B)
  transpose_x_kernel<<<(Tt / 2) * (Ii / 64), 256, 0, stream>>>(x, x2);

  // CSR build (all three pair-padded for int4 loads)
  hist3_kernel<<<1024, 256, 0, stream>>>(ih_rows, nnz_ih, ih_cur,
                                         hh_rows, nnz_hh, hh_cur,
                                         ho_rows, nnz_ho, ho_cur);
  scan3_kernel<<<3, 1024, 0, stream>>>(ih_cur, Hh, ih_rs, 1,
                                       hh_cur, Hh, hh_rs, 1,
                                       ho_cur, Oo, ho_rs, 1);
  scatter3_kernel<<<1024, 256, 0, stream>>>(
      ih_rows, ih_cols, ih_vals, nnz_ih, ih_cur, ih_ent,
      hh_rows, hh_cols, hh_vals, nnz_hh, hh_cur, hh_ent,
      ho_rows, ho_cols, ho_vals, nnz_ho, ho_cur, ho_ent);

  // pre[t][r][b] for all t; XCD-pinned time chunks
  preih_kernel<<<8 * Hh / 4, 256, 0, stream>>>(
      ih_rs, ih_cur, (const int4*)ih_ent, hh_bias, x2, preAll);

  // Recurrence: persistent cooperative kernel with light flag barrier,
  // fallback to per-step dispatches if co-residency isn't available.
  int maxB = 0;
  (void)hipOccupancyMaxActiveBlocksPerMultiprocessor(&maxB, rnn_pipe, 256, 0);
  if (maxB >= 4) {
    int blocks = (maxB >= 8) ? 2048 : 1024;
    int nwaves = blocks * 4;
    int nrw = Hh / nwaves;               // 1 or 2 rows per wave
    unsigned int nblocks = (unsigned int)blocks;
    void* args[] = {(void*)&hh_rs, (void*)&hh_cur, (void*)&hh_ent,
                    (void*)&preAll, (void*)&hAll,
                    (void*)&arrive, (void*)&goflag,
                    (void*)&nrw, (void*)&nwaves, (void*)&nblocks};
    hipLaunchCooperativeKernel((const void*)rnn_pipe, dim3(blocks), dim3(256),
                               args, 0, stream);
  } else {
    for (int t = 0; t < Tt; t++) {
      step_kernel<<<Hh / 4, 256, 0, stream>>>(
          hh_rs, hh_cur, (const int4*)hh_ent,
          preAll + (size_t)t * Hh * Bb,
          hAll + (size_t)t * Hh * Bb,
          hAll + (size_t)(t + 1) * Hh * Bb);
    }
  }

  // Output spmm (XCD t-partitioned) + final transpose
  out_kernel<<<2048, 256, 0, stream>>>(
      ho_rs, ho_cur, (const int4*)ho_ent, ho_bias, hAll, out_tmp);
  transpose_out_kernel<<<Tt * (Oo / 64), 256, 0, stream>>>(out_tmp, out);

  (void)n_in; (void)out_size; (void)ws_size;
}

// Round 9
// 815.604 us; speedup vs baseline: 1.6608x; 1.6608x over previous
//
#include <hip/hip_runtime.h>
#include <hip/hip_fp16.h>

// Problem constants (fixed by the reference)
constexpr int Bb = 32;     // batch
constexpr int Tt = 32;     // time steps
constexpr int Ii = 8192;   // input dim
constexpr int Hh = 8192;   // hidden dim
constexpr int Oo = 2048;   // output dim
constexpr int TB = Tt * Bb;  // halves per x2 column = 1024
constexpr int TCH = 4;       // timesteps per XCD chunk

// Entry packing: lo16 = col (u16), hi16 = fp16 value bits. 4 B/entry.
// Rows padded to multiples of 8 entries (32 B) -> int4 loads cover 4 entries.

__device__ __forceinline__ float entval(uint32_t u) {
  return __half2float(__ushort_as_half((unsigned short)(u >> 16)));
}

// ---------------- x transpose: (B,T,I) fp32 -> (I,T,B) fp16 ----------------
__global__ void transpose_x_kernel(const float* __restrict__ x, __half2* __restrict__ x2) {
  int blk = blockIdx.x;          // (Tt/2) * (Ii/64) = 2048 blocks
  int tp = blk >> 7;
  int ib = blk & 127;
  int t0 = tp * 2;
  int i0 = ib * 64;
  __shared__ float lds[64][65];
  int tid = threadIdx.x;
  for (int idx = tid; idx < 64 * 64; idx += 256) {
    int row = idx >> 6, il = idx & 63;     // coalesced reads along i
    int tt = row >> 5, bb = row & 31;
    lds[il][row] = x[(size_t)bb * Tt * Ii + (size_t)(t0 + tt) * Ii + i0 + il];
  }
  __syncthreads();
  for (int idx = tid; idx < 64 * 32; idx += 256) {
    int il = idx >> 5;
    int q = idx & 31;
    int tt = q >> 4, p = q & 15;           // b-pair p -> batches 2p, 2p+1
    float lo = lds[il][tt * 32 + 2 * p];
    float hi = lds[il][tt * 32 + 2 * p + 1];
    x2[(size_t)(i0 + il) * (TB / 2) + (size_t)(t0 + tt) * 16 + p] = __floats2half2_rn(lo, hi);
  }
}

// ---------------- CSR build (merged kernels) ----------------
__global__ void hist3_kernel(const int* __restrict__ r1, int n1, int* __restrict__ c1,
                             const int* __restrict__ r2, int n2, int* __restrict__ c2,
                             const int* __restrict__ r3, int n3, int* __restrict__ c3) {
  int i = blockIdx.x * blockDim.x + threadIdx.x;
  int stride = gridDim.x * blockDim.x;
  for (int j = i; j < n1; j += stride) atomicAdd(&c1[r1[j]], 1);
  for (int j = i; j < n2; j += stride) atomicAdd(&c2[r2[j]], 1);
  for (int j = i; j < n3; j += stride) atomicAdd(&c3[r3[j]], 1);
}

// Exclusive scan; row counts rounded up to multiple of 8 entries (32 B-aligned
// row starts for int4 loads). One block per array.
__global__ void scan3_kernel(int* __restrict__ c1, int n1, int* __restrict__ r1,
                             int* __restrict__ c2, int n2, int* __restrict__ r2,
                             int* __restrict__ c3, int n3, int* __restrict__ r3) {
  int* cnt_cursor; int n; int* row_start;
  if (blockIdx.x == 0)      { cnt_cursor = c1; n = n1; row_start = r1; }
  else if (blockIdx.x == 1) { cnt_cursor = c2; n = n2; row_start = r2; }
  else                      { cnt_cursor = c3; n = n3; row_start = r3; }
  __shared__ int sums[1024];
  int tid = threadIdx.x;
  int chunk = (n + 1023) >> 10;
  int base = tid * chunk;
  int s = 0;
  for (int i = 0; i < chunk; i++) {
    int idx = base + i;
    if (idx < n) s += (cnt_cursor[idx] + 7) & ~7;
  }
  sums[tid] = s;
  __syncthreads();
  for (int off = 1; off < 1024; off <<= 1) {
    int other = (tid >= off) ? sums[tid - off] : 0;
    __syncthreads();
    sums[tid] += other;
    __syncthreads();
  }
  int run = sums[tid] - s;
  for (int i = 0; i < chunk; i++) {
    int idx = base + i;
    if (idx < n) {
      int v = cnt_cursor[idx];
      row_start[idx] = run;
      cnt_cursor[idx] = run;
      run += (v + 7) & ~7;
    }
  }
  if (tid == 1023) row_start[n] = sums[1023];
}

__global__ void scatter3_kernel(
    const int* __restrict__ r1, const int* __restrict__ co1, const float* __restrict__ v1,
    int n1, int* __restrict__ cu1, uint32_t* __restrict__ e1,
    const int* __restrict__ r2, const int* __restrict__ co2, const float* __restrict__ v2,
    int n2, int* __restrict__ cu2, uint32_t* __restrict__ e2,
    const int* __restrict__ r3, const int* __restrict__ co3, const float* __restrict__ v3,
    int n3, int* __restrict__ cu3, uint32_t* __restrict__ e3) {
  int i = blockIdx.x * blockDim.x + threadIdx.x;
  int stride = gridDim.x * blockDim.x;
  for (int j = i; j < n1; j += stride) {
    int pos = atomicAdd(&cu1[r1[j]], 1);
    e1[pos] = ((uint32_t)__half_as_ushort(__float2half_rn(v1[j])) << 16) | (uint32_t)co1[j];
  }
  for (int j = i; j < n2; j += stride) {
    int pos = atomicAdd(&cu2[r2[j]], 1);
    e2[pos] = ((uint32_t)__half_as_ushort(__float2half_rn(v2[j])) << 16) | (uint32_t)co2[j];
  }
  for (int j = i; j < n3; j += stride) {
    int pos = atomicAdd(&cu3[r3[j]], 1);
    e3[pos] = ((uint32_t)__half_as_ushort(__float2half_rn(v3[j])) << 16) | (uint32_t)co3[j];
  }
}

// ---------------- preIH, XCD-pinned time chunks, fp16 data ----------------
// xcd = blockIdx&7 owns t-chunk [4*xcd, 4*xcd+4): 2 MB fp16 x2 slice L2-resident.
// Lane covers (tt = lane>>4, b-pair = lane&15); gather = uint (2 fp16) -> 256 B/entry.
__global__ void __launch_bounds__(256, 8) preih_kernel(
    const int* __restrict__ ih_rs, const int* __restrict__ ih_cur,
    const uint32_t* __restrict__ ih_ent,
    const float* __restrict__ hh_bias, const __half* __restrict__ x2h,
    __half2* __restrict__ preAll) {
  int xcd = blockIdx.x & 7;
  int r = ((blockIdx.x >> 3) << 2) + (threadIdx.x >> 6);
  int lane = threadIdx.x & 63;
  int t0 = xcd * TCH;
  int s0  = __builtin_amdgcn_readfirstlane(ih_rs[r]);       // multiple of 8
  int cnt = __builtin_amdgcn_readfirstlane(ih_cur[r]) - s0;
  int nb = (cnt + 7) >> 3;                                  // 8-entry blocks
  const int4* ep = (const int4*)(ih_ent + s0);
  const uint32_t* xb = (const uint32_t*)(x2h + (size_t)t0 * Bb);  // + c*(TB/2) uints

  float2 a0 = {0.f, 0.f}, a1 = {0.f, 0.f}, a2 = {0.f, 0.f}, a3 = {0.f, 0.f};
  int4 f0 = ep[0], f1 = ep[1];
  for (int i = 0; i < nb; i++) {
    int4 e0 = f0, e1 = f1;
    f0 = ep[2 * i + 2];            // prefetch next block during gathers
    f1 = ep[2 * i + 3];
    uint32_t u0 = (uint32_t)e0.x, u1 = (uint32_t)e0.y, u2 = (uint32_t)e0.z, u3 = (uint32_t)e0.w;
    uint32_t u4 = (uint32_t)e1.x, u5 = (uint32_t)e1.y, u6 = (uint32_t)e1.z, u7 = (uint32_t)e1.w;
    uint32_t g0 = xb[(size_t)(u0 & 0xffff) * (TB / 2) + lane];
    uint32_t g1 = xb[(size_t)(u1 & 0xffff) * (TB / 2) + lane];
    uint32_t g2 = xb[(size_t)(u2 & 0xffff) * (TB / 2) + lane];
    uint32_t g3 = xb[(size_t)(u3 & 0xffff) * (TB / 2) + lane];
    uint32_t g4 = xb[(size_t)(u4 & 0xffff) * (TB / 2) + lane];
    uint32_t g5 = xb[(size_t)(u5 & 0xffff) * (TB / 2) + lane];
    uint32_t g6 = xb[(size_t)(u6 & 0xffff) * (TB / 2) + lane];
    uint32_t g7 = xb[(size_t)(u7 & 0xffff) * (TB / 2) + lane];
    float v0 = entval(u0), v1 = entval(u1), v2 = entval(u2), v3 = entval(u3);
    float v4 = entval(u4), v5 = entval(u5), v6 = entval(u6), v7 = entval(u7);
    float2 x0 = __half22float2(*(__half2*)&g0), x1 = __half22float2(*(__half2*)&g1);
    float2 x2v = __half22float2(*(__half2*)&g2), x3 = __half22float2(*(__half2*)&g3);
    float2 x4 = __half22float2(*(__half2*)&g4), x5 = __half22float2(*(__half2*)&g5);
    float2 x6 = __half22float2(*(__half2*)&g6), x7 = __half22float2(*(__half2*)&g7);
    a0.x += v0 * x0.x;  a0.y += v0 * x0.y;   a0.x += v4 * x4.x;  a0.y += v4 * x4.y;
    a1.x += v1 * x1.x;  a1.y += v1 * x1.y;   a1.x += v5 * x5.x;  a1.y += v5 * x5.y;
    a2.x += v2 * x2v.x; a2.y += v2 * x2v.y;  a2.x += v6 * x6.x;  a2.y += v6 * x6.y;
    a3.x += v3 * x3.x;  a3.y += v3 * x3.y;   a3.x += v7 * x7.x;  a3.y += v7 * x7.y;
  }
  float bias = hh_bias[r];
  float sx = ((a0.x + a1.x) + (a2.x + a3.x)) + bias;
  float sy = ((a0.y + a1.y) + (a2.y + a3.y)) + bias;
  int tt = lane >> 4, p = lane & 15;
  preAll[((size_t)(t0 + tt) * Hh + r) * 16 + p] = __floats2half2_rn(sx, sy);
}

// ---------------- One recurrence step: h_{t+1} = sigmoid(pre_t + HH @ h_t) ----------------
// One wave per row; fp16 h/pre, packed 4B entries, entry prefetch.
__global__ void __launch_bounds__(256, 8) step_kernel(
    const int* __restrict__ hh_rs, const int* __restrict__ hh_cur,
    const uint32_t* __restrict__ hh_ent,
    const __half* __restrict__ pre_t,
    const __half* __restrict__ hprev,
    __half* __restrict__ hnext) {
  int r = (blockIdx.x * 256 + threadIdx.x) >> 6;
  int lane = threadIdx.x & 63;
  int h = lane >> 5, b = lane & 31;
  int s0  = __builtin_amdgcn_readfirstlane(hh_rs[r]);       // multiple of 8
  int cnt = __builtin_amdgcn_readfirstlane(hh_cur[r]) - s0;
  int nb = (cnt + 7) >> 3;
  const int4* ep = (const int4*)(hh_ent + s0);
  float pre = __half2float(pre_t[(r << 5) + b]);

  float a0 = 0.f, a1 = 0.f, a2 = 0.f, a3 = 0.f;
  int4 f0 = ep[0], f1 = ep[1];
  for (int i = 0; i < nb; i++) {
    int4 e0 = f0, e1 = f1;
    f0 = ep[2 * i + 2];
    f1 = ep[2 * i + 3];
    uint32_t u0 = (uint32_t)(h ? e0.y : e0.x);   // parity split across half-waves
    uint32_t u1 = (uint32_t)(h ? e0.w : e0.z);
    uint32_t u2 = (uint32_t)(h ? e1.y : e1.x);
    uint32_t u3 = (uint32_t)(h ? e1.w : e1.z);
    float h0 = __half2float(hprev[(((size_t)(u0 & 0xffff)) << 5) + b]);
    float h1 = __half2float(hprev[(((size_t)(u1 & 0xffff)) << 5) + b]);
    float h2 = __half2float(hprev[(((size_t)(u2 & 0xffff)) << 5) + b]);
    float h3 = __half2float(hprev[(((size_t)(u3 & 0xffff)) << 5) + b]);
    a0 += entval(u0) * h0;
    a1 += entval(u1) * h1;
    a2 += entval(u2) * h2;
    a3 += entval(u3) * h3;
  }
  float acc = (a0 + a1) + (a2 + a3);
  acc += __shfl_xor(acc, 32, 64);
  float hv = 1.0f / (1.0f + __expf(-(pre + acc)));
  if (h == 0) hnext[(r << 5) + b] = __float2half_rn(hv);
}

// ---------------- Output spmm, XCD-partitioned by time, fp16 h ----------------
__global__ void __launch_bounds__(256, 8) out_kernel(
    const int* __restrict__ ho_rs, const int* __restrict__ ho_cur,
    const uint32_t* __restrict__ ho_ent,
    const float* __restrict__ ho_bias, const __half* __restrict__ hAll,
    float* __restrict__ out_tmp) {
  int xcd = blockIdx.x & 7;
  int w   = (blockIdx.x >> 3) * 4 + (threadIdx.x >> 6);
  int lane = threadIdx.x & 63;
  int h = lane >> 5, b = lane & 31;
  int t0 = xcd * 4;
  constexpr size_t HS = (size_t)Hh * Bb;
  const __half* hbase = hAll + (size_t)(t0 + 1) * HS;

  for (int o = w; o < Oo; o += 1024) {
    int s0  = __builtin_amdgcn_readfirstlane(ho_rs[o]);
    int cnt = __builtin_amdgcn_readfirstlane(ho_cur[o]) - s0;
    int nb = (cnt + 7) >> 3;
    const int4* ep = (const int4*)(ho_ent + s0);
    float bias = (h == 0) ? ho_bias[o] : 0.f;
    float A0 = bias, A1 = bias, A2 = bias, A3 = bias;
    float B0 = 0.f, B1 = 0.f, B2 = 0.f, B3 = 0.f;
    for (int i = 0; i < nb; i++) {
      int4 e0 = ep[2 * i], e1 = ep[2 * i + 1];
      uint32_t u0 = (uint32_t)(h ? e0.y : e0.x);
      uint32_t u1 = (uint32_t)(h ? e0.w : e0.z);
      uint32_t u2 = (uint32_t)(h ? e1.y : e1.x);
      uint32_t u3 = (uint32_t)(h ? e1.w : e1.z);
      const __half* p0 = hbase + (((size_t)(u0 & 0xffff)) << 5) + b;
      const __half* p1 = hbase + (((size_t)(u1 & 0xffff)) << 5) + b;
      const __half* p2 = hbase + (((size_t)(u2 & 0xffff)) << 5) + b;
      const __half* p3 = hbase + (((size_t)(u3 & 0xffff)) << 5) + b;
      float v0 = entval(u0), v1 = entval(u1), v2 = entval(u2), v3 = entval(u3);
      A0 += v0 * __half2float(p0[0]);
      A1 += v0 * __half2float(p0[HS]);
      A2 += v0 * __half2float(p0[2 * HS]);
      A3 += v0 * __half2float(p0[3 * HS]);
      B0 += v1 * __half2float(p1[0]);
      B1 += v1 * __half2float(p1[HS]);
      B2 += v1 * __half2float(p1[2 * HS]);
      B3 += v1 * __half2float(p1[3 * HS]);
      A0 += v2 * __half2float(p2[0]);
      A1 += v2 * __half2float(p2[HS]);
      A2 += v2 * __half2float(p2[2 * HS]);
      A3 += v2 * __half2float(p2[3 * HS]);
      B0 += v3 * __half2float(p3[0]);
      B1 += v3 * __half2float(p3[HS]);
      B2 += v3 * __half2float(p3[2 * HS]);
      B3 += v3 * __half2float(p3[3 * HS]);
    }
    A0 += B0; A1 += B1; A2 += B2; A3 += B3;
    A0 += __shfl_xor(A0, 32, 64);
    A1 += __shfl_xor(A1, 32, 64);
    A2 += __shfl_xor(A2, 32, 64);
    A3 += __shfl_xor(A3, 32, 64);
    if (h == 0) {
      out_tmp[((size_t)(t0 + 0) * Oo + o) * Bb + b] = A0;
      out_tmp[((size_t)(t0 + 1) * Oo + o) * Bb + b] = A1;
      out_tmp[((size_t)(t0 + 2) * Oo + o) * Bb + b] = A2;
      out_tmp[((size_t)(t0 + 3) * Oo + o) * Bb + b] = A3;
    }
  }
}

// ---------------- out transpose: (T,O,B) -> (B,T,O), fp32 ----------------
__global__ void transpose_out_kernel(const float* __restrict__ out_tmp, float* __restrict__ dout) {
  int blk = blockIdx.x;
  int t  = blk >> 5;
  int o0 = (blk & 31) << 6;
  __shared__ float lds[64][33];
  int tid = threadIdx.x;
  for (int idx = tid; idx < 64 * 32; idx += 256) {
    int ol = idx >> 5, bb = idx & 31;
    lds[ol][bb] = out_tmp[(size_t)t * Oo * Bb + (size_t)(o0 + ol) * Bb + bb];
  }
  __syncthreads();
  for (int idx = tid; idx < 32 * 64; idx += 256) {
    int bb = idx >> 6, ol = idx & 63;
    dout[(size_t)bb * Tt * Oo + (size_t)t * Oo + o0 + ol] = lds[ol][bb];
  }
}

extern "C" void kernel_launch(void* const* d_in, const int* in_sizes, int n_in,
                              void* d_out, int out_size, void* d_ws, size_t ws_size,
                              hipStream_t stream) {
  const float* x       = (const float*)d_in[0];
  const int*   hh_rows = (const int*)d_in[1];
  const int*   hh_cols = (const int*)d_in[2];
  const float* hh_vals = (const float*)d_in[3];
  const float* hh_bias = (const float*)d_in[4];
  const int*   ih_rows = (const int*)d_in[5];
  const int*   ih_cols = (const int*)d_in[6];
  const float* ih_vals = (const float*)d_in[7];
  const int*   ho_rows = (const int*)d_in[8];
  const int*   ho_cols = (const int*)d_in[9];
  const float* ho_vals = (const float*)d_in[10];
  const float* ho_bias = (const float*)d_in[11];
  float* out = (float*)d_out;

  const int nnz_hh = in_sizes[1];
  const int nnz_ih = in_sizes[5];
  const int nnz_ho = in_sizes[8];

  // Workspace carve-up (~70 MB)
  char* w = (char*)d_ws;
  size_t off = 0;
  auto alloc = [&](size_t bytes) -> void* {
    void* p = w + off;
    off += (bytes + 255) & ~(size_t)255;
    return p;
  };
  __half* x2h    = (__half*)alloc(2 * (size_t)Ii * TB);                 // 16 MB
  __half* hAll   = (__half*)alloc(2 * (size_t)(Tt + 1) * Hh * Bb);      // 16.5 MB
  __half* preAll = (__half*)alloc(2 * (size_t)Tt * Hh * Bb);            // 16 MB
  float* out_tmp = (float*)alloc(4 * (size_t)Tt * Oo * Bb);             // 8 MB
  int*  ih_rs  = (int*)alloc(4 * (size_t)(Hh + 1));
  int*  hh_rs  = (int*)alloc(4 * (size_t)(Hh + 1));
  int*  ho_rs  = (int*)alloc(4 * (size_t)(Oo + 1));
  size_t zero_off0 = off;
  int*  cur_all = (int*)alloc(4 * (size_t)(Hh + Hh + Oo));
  int*  ih_cur = cur_all;
  int*  hh_cur = cur_all + Hh;
  int*  ho_cur = cur_all + 2 * Hh;
  size_t zero_bytes = off - zero_off0;
  size_t ent_off0 = off;
  uint32_t* ih_ent = (uint32_t*)alloc(4 * ((size_t)nnz_ih + 8 * Hh + 64));  // pad8 + slack
  uint32_t* hh_ent = (uint32_t*)alloc(4 * ((size_t)nnz_hh + 8 * Hh + 64));
  uint32_t* ho_ent = (uint32_t*)alloc(4 * ((size_t)nnz_ho + 8 * Oo + 64));
  size_t ent_bytes = off - ent_off0;

  // Init (3 memsets)
  hipMemsetAsync(hAll, 0, 2 * (size_t)Hh * Bb, stream);   // h_{-1} = 0 (fp16 zeros)
  hipMemsetAsync(w + zero_off0, 0, zero_bytes, stream);
  hipMemsetAsync(w + ent_off0, 0, ent_bytes, stream);     // pad entries = col 0, val 0

  // x -> (I,T,B) fp16
  transpose_x_kernel<<<(Tt / 2) * (Ii / 64), 256, 0, stream>>>(x, (__half2*)x2h);

  // CSR build (rows padded to multiples of 8 entries; packed 4B entries)
  hist3_kernel<<<1024, 256, 0, stream>>>(ih_rows, nnz_ih, ih_cur,
                                         hh_rows, nnz_hh, hh_cur,
                                         ho_rows, nnz_ho, ho_cur);
  scan3_kernel<<<3, 1024, 0, stream>>>(ih_cur, Hh, ih_rs,
                                       hh_cur, Hh, hh_rs,
                                       ho_cur, Oo, ho_rs);
  scatter3_kernel<<<1024, 256, 0, stream>>>(
      ih_rows, ih_cols, ih_vals, nnz_ih, ih_cur, ih_ent,
      hh_rows, hh_cols, hh_vals, nnz_hh, hh_cur, hh_ent,
      ho_rows, ho_cols, ho_vals, nnz_ho, ho_cur, ho_ent);

  // pre[t][r][b] fp16, XCD-pinned time chunks
  preih_kernel<<<8 * Hh / 4, 256, 0, stream>>>(
      ih_rs, ih_cur, ih_ent, hh_bias, x2h, (__half2*)preAll);

  // Recurrence: one dispatch per step
  for (int t = 0; t < Tt; t++) {
    step_kernel<<<Hh / 4, 256, 0, stream>>>(
        hh_rs, hh_cur, hh_ent,
        preAll + (size_t)t * Hh * Bb,
        hAll + (size_t)t * Hh * Bb,
        hAll + (size_t)(t + 1) * Hh * Bb);
  }

  // Output spmm (XCD t-partitioned) + final transpose
  out_kernel<<<2048, 256, 0, stream>>>(
      ho_rs, ho_cur, ho_ent, ho_bias, hAll, out_tmp);
  transpose_out_kernel<<<Tt * (Oo / 64), 256, 0, stream>>>(out_tmp, out);

  (void)n_in; (void)out_size; (void)ws_size;
}